// Round 12
// baseline (559.005 us; speedup 1.0000x reference)
//
#include <hip/hip_runtime.h>
#include <math.h>

#define NN   40000
#define EE   640000
#define ETOT (EE + NN)          // 680000 edges incl self-loops
#define NBLK ((NN + 255) / 256) // 157

typedef short bf16x8 __attribute__((ext_vector_type(8)));
typedef float f32x4  __attribute__((ext_vector_type(4)));

__device__ __forceinline__ unsigned short f2bf(float f) {
    unsigned int u = __float_as_uint(f);
    u += 0x7fff + ((u >> 16) & 1);          // RNE
    return (unsigned short)(u >> 16);
}
__device__ __forceinline__ float bf2f(unsigned short h) {
    return __uint_as_float(((unsigned int)h) << 16);
}

// ---------------------------------------------------------------- CSR build
__global__ void count_k(const int* __restrict__ ei, int* __restrict__ counts) {
    int e = blockIdx.x * 256 + threadIdx.x;
    if (e >= ETOT) return;
    int d = (e < EE) ? ei[EE + e] : (e - EE);
    atomicAdd(&counts[d], 1);
}

__global__ __launch_bounds__(256) void scan_k(const int* __restrict__ in,
                                              int* __restrict__ out,
                                              int* __restrict__ sums, int n) {
    __shared__ int tmp[256];
    int i = blockIdx.x * 256 + threadIdx.x;
    int v = (i < n) ? in[i] : 0;
    tmp[threadIdx.x] = v;
    __syncthreads();
    #pragma unroll
    for (int off = 1; off < 256; off <<= 1) {
        int t = (threadIdx.x >= off) ? tmp[threadIdx.x - off] : 0;
        __syncthreads();
        tmp[threadIdx.x] += t;
        __syncthreads();
    }
    if (i < n) out[i] = tmp[threadIdx.x] - v;   // exclusive
    if (sums != nullptr && threadIdx.x == 255) sums[blockIdx.x] = tmp[255];
}

__global__ void add_off_k(int* __restrict__ data, const int* __restrict__ offs) {
    int i = blockIdx.x * 256 + threadIdx.x;
    if (i < NN) data[i] += offs[blockIdx.x];
    if (blockIdx.x == 0 && threadIdx.x == 0) data[NN] = ETOT;
}

__global__ void scatter_k(const int* __restrict__ ei, const int* __restrict__ rowptr,
                          int* __restrict__ cursor, int* __restrict__ csr_src) {
    int e = blockIdx.x * 256 + threadIdx.x;
    if (e >= ETOT) return;
    int s, d;
    if (e < EE) { s = ei[e]; d = ei[EE + e]; } else { s = d = e - EE; }
    int pos = rowptr[d] + atomicAdd(&cursor[d], 1);
    csr_src[pos] = s;
}

// ---------------------------------------------------------------- prep kernels
// x [NN][50] f32 -> xb [NN][64] bf16 (zero pad)
__global__ __launch_bounds__(256) void xprep_k(const float* __restrict__ x,
                                               unsigned short* __restrict__ xb) {
    int idx = blockIdx.x * 256 + threadIdx.x;   // NN*64 total
    if (idx >= NN * 64) return;
    int m = idx >> 6, k = idx & 63;
    xb[idx] = (k < 50) ? f2bf(x[(size_t)m * 50 + k]) : (unsigned short)0;
}

// layer-1 combined B: bt1[c][kk], kk<256: block-diag W1; kk in [256,320): Wl1
__global__ void w1prep_k(const float* __restrict__ W1, const float* __restrict__ Wl1,
                         unsigned short* __restrict__ bt) {
    int c = blockIdx.x;   // 0..255
    int hc = c >> 6;
    for (int kk = threadIdx.x; kk < 320; kk += blockDim.x) {
        float v = 0.f;
        if (kk < 256) {
            int h = kk >> 6, k = kk & 63;
            if (h == hc && k < 50) v = W1[(size_t)k * 256 + c];
        } else {
            int k = kk - 256;
            if (k < 50) v = Wl1[(size_t)k * 256 + c];
        }
        bt[(size_t)c * 320 + kk] = f2bf(v);
    }
}

// layer-2 combined B: w2c[c][k], c<256: W2 col c; c in [256,512): Wl2 col c-256
__global__ void w2prep_k(const float* __restrict__ W2, const float* __restrict__ Wl2,
                         unsigned short* __restrict__ wt) {
    int c = blockIdx.x;   // 0..511
    for (int k = threadIdx.x; k < 256; k += blockDim.x) {
        float v = (c < 256) ? W2[(size_t)k * 256 + c] : Wl2[(size_t)k * 256 + (c - 256)];
        wt[(size_t)c * 256 + k] = f2bf(v);
    }
}

// layer-3 combined B: bt3[c][kk], kk<1536: W3[k, h*121+c]/6; kk in [1536,1792): Wl3
__global__ void w3prep_k(const float* __restrict__ W3, const float* __restrict__ Wl3,
                         unsigned short* __restrict__ bt) {
    int c = blockIdx.x;   // 0..120
    for (int kk = threadIdx.x; kk < 1792; kk += blockDim.x) {
        float v;
        if (kk < 1536) {
            int h = kk >> 8, k = kk & 255;
            v = W3[(size_t)k * 726 + h * 121 + c] * (1.f / 6.f);
        } else {
            int k = kk - 1536;
            v = Wl3[(size_t)k * 121 + c];
        }
        bt[(size_t)c * 1792 + kk] = f2bf(v);
    }
}

// attention projection matrix, bf16: Vt[j][k], j<16: va_j (j<H), j>=16: vb_{j-16}
__global__ void attvec2_k(const float* __restrict__ W, const float* __restrict__ as_,
                          const float* __restrict__ ad, unsigned short* __restrict__ Vt,
                          int Kreal, int Kpad, int H, int OC) {
    int idx = blockIdx.x * 256 + threadIdx.x;   // Kpad*32
    if (idx >= Kpad * 32) return;
    int k = idx >> 5, j = idx & 31;
    int h = j & 15;
    float s = 0.f;
    if (k < Kreal && h < H) {
        const float* wrow = W + (size_t)k * (H * OC) + h * OC;
        const float* av = (j < 16) ? as_ : ad;
        for (int c = 0; c < OC; ++c) s += wrow[c] * av[h * OC + c];
    }
    Vt[(size_t)j * Kpad + k] = f2bf(s);
}

// merged bias sums: o1=b1+bl1 [256], o2=b2+bl2 [256], o3=b3+bl3 [121]
__global__ void biases_k(const float* __restrict__ b1, const float* __restrict__ bl1,
                         const float* __restrict__ b2, const float* __restrict__ bl2,
                         const float* __restrict__ b3, const float* __restrict__ bl3,
                         float* __restrict__ o1, float* __restrict__ o2,
                         float* __restrict__ o3) {
    int i = threadIdx.x;
    if (i < 256) { o1[i] = b1[i] + bl1[i]; o2[i] = b2[i] + bl2[i]; }
    if (i < 121) o3[i] = b3[i] + bl3[i];
}

// ---------------------------------------------------------------- bf16 MFMA GEMM (128x128 tile)
// C[M,N] = A[M,K] @ Bt[N,K]^T.  A,Bt bf16 row-major; K % 32 == 0.
// MODE 3: Cb=AB bf16 | MODE 6: Cb=elu(AB+bias) bf16
template <int MODE>
__global__ __launch_bounds__(256, 4) void gemm_bf16_k(const unsigned short* __restrict__ A,
                                                      const unsigned short* __restrict__ Bt,
                                                      const float* __restrict__ bias,
                                                      float* __restrict__ C,
                                                      unsigned short* __restrict__ Cb,
                                                      int M, int N, int K) {
    // 80B row stride (40 shorts): ds_read_b128 start banks spread evenly
    __shared__ unsigned short As[128 * 40];
    __shared__ unsigned short Bs[128 * 40];
    const int tid  = threadIdx.x;
    const int lane = tid & 63;
    const int wv   = tid >> 6;
    const int wm   = wv >> 1, wn = wv & 1;
    const int r16  = lane & 15, kg = lane >> 4;
    const int bm   = blockIdx.y * 128, bn = blockIdx.x * 128;

    f32x4 acc[4][4];
    #pragma unroll
    for (int m = 0; m < 4; ++m)
        #pragma unroll
        for (int n = 0; n < 4; ++n) acc[m][n] = (f32x4){0.f, 0.f, 0.f, 0.f};

    const bf16x8 zero8 = (bf16x8){0,0,0,0,0,0,0,0};
    for (int k0 = 0; k0 < K; k0 += 32) {
        #pragma unroll
        for (int i = 0; i < 2; ++i) {
            int idx = tid + i * 256;            // 0..511
            int r = idx >> 2, c = idx & 3;      // row, 16B chunk
            int gr = bm + r;
            bf16x8 v = zero8;
            if (gr < M) v = *(const bf16x8*)(A + (size_t)gr * K + k0 + c * 8);
            *(bf16x8*)((char*)As + r * 80 + c * 16) = v;
            int gn = bn + r;
            bf16x8 w = zero8;
            if (gn < N) w = *(const bf16x8*)(Bt + (size_t)gn * K + k0 + c * 8);
            *(bf16x8*)((char*)Bs + r * 80 + c * 16) = w;
        }
        __syncthreads();
        bf16x8 fa[4], fb[4];
        #pragma unroll
        for (int m = 0; m < 4; ++m)
            fa[m] = *(const bf16x8*)((const char*)As + (wm * 64 + m * 16 + r16) * 80 + kg * 16);
        #pragma unroll
        for (int n = 0; n < 4; ++n)
            fb[n] = *(const bf16x8*)((const char*)Bs + (wn * 64 + n * 16 + r16) * 80 + kg * 16);
        #pragma unroll
        for (int m = 0; m < 4; ++m)
            #pragma unroll
            for (int n = 0; n < 4; ++n)
                acc[m][n] = __builtin_amdgcn_mfma_f32_16x16x32_bf16(fa[m], fb[n], acc[m][n], 0, 0, 0);
        __syncthreads();
    }
    #pragma unroll
    for (int m = 0; m < 4; ++m) {
        #pragma unroll
        for (int r = 0; r < 4; ++r) {
            int gr = bm + wm * 64 + m * 16 + kg * 4 + r;
            if (gr >= M) continue;
            #pragma unroll
            for (int n = 0; n < 4; ++n) {
                int gc = bn + wn * 64 + n * 16 + r16;
                if (gc >= N) continue;
                size_t o = (size_t)gr * N + gc;
                float v = acc[m][n][r];
                if (MODE == 3) {
                    Cb[o] = f2bf(v);
                } else if (MODE == 6) {
                    float w = v + bias[gc];
                    w = (w > 0.f) ? w : expm1f(w);
                    Cb[o] = f2bf(w);
                }
            }
        }
    }
}

// ---------------------------------------------------------------- skinny GEMM (32xN tile, N<=128, BK=64)
// 144B LDS row stride (72 shorts): banks spread; two 32-k halves per row.
__global__ __launch_bounds__(256) void gemm_skinny_k(const unsigned short* __restrict__ A,
                                                     const unsigned short* __restrict__ Bt,
                                                     const float* __restrict__ bias,
                                                     float* __restrict__ C,
                                                     int M, int N, int K) {
    __shared__ unsigned short As[32 * 72];
    __shared__ unsigned short Bs[128 * 72];
    const int tid  = threadIdx.x;
    const int lane = tid & 63;
    const int wv   = tid >> 6;
    const int r16  = lane & 15, kg = lane >> 4;
    const int bm   = blockIdx.x * 32;

    f32x4 acc[2][2];
    #pragma unroll
    for (int m = 0; m < 2; ++m)
        #pragma unroll
        for (int n = 0; n < 2; ++n) acc[m][n] = (f32x4){0.f, 0.f, 0.f, 0.f};

    const bf16x8 zero8 = (bf16x8){0,0,0,0,0,0,0,0};
    for (int k0 = 0; k0 < K; k0 += 64) {
        {                                       // A tile: 32 rows x 8 chunks (256 total)
            int r = tid >> 3, c = tid & 7;
            *(bf16x8*)((char*)As + r * 144 + c * 16) =
                *(const bf16x8*)(A + (size_t)(bm + r) * K + k0 + c * 8);
        }
        #pragma unroll
        for (int i = 0; i < 4; ++i) {           // B tile: 128 rows x 8 chunks (1024 total)
            int idx = tid + i * 256;
            int r = idx >> 3, c = idx & 7;
            bf16x8 w = zero8;
            if (r < N) w = *(const bf16x8*)(Bt + (size_t)r * K + k0 + c * 8);
            *(bf16x8*)((char*)Bs + r * 144 + c * 16) = w;
        }
        __syncthreads();
        #pragma unroll
        for (int half = 0; half < 2; ++half) {
            bf16x8 fa[2], fb[2];
            int koff = half * 64 + kg * 16;     // byte offset within row
            #pragma unroll
            for (int m = 0; m < 2; ++m)
                fa[m] = *(const bf16x8*)((const char*)As + (m * 16 + r16) * 144 + koff);
            #pragma unroll
            for (int n = 0; n < 2; ++n)
                fb[n] = *(const bf16x8*)((const char*)Bs + (wv * 32 + n * 16 + r16) * 144 + koff);
            #pragma unroll
            for (int m = 0; m < 2; ++m)
                #pragma unroll
                for (int n = 0; n < 2; ++n)
                    acc[m][n] = __builtin_amdgcn_mfma_f32_16x16x32_bf16(fa[m], fb[n], acc[m][n], 0, 0, 0);
        }
        __syncthreads();
    }
    #pragma unroll
    for (int m = 0; m < 2; ++m) {
        #pragma unroll
        for (int r = 0; r < 4; ++r) {
            int gr = bm + m * 16 + kg * 4 + r;
            #pragma unroll
            for (int n = 0; n < 2; ++n) {
                int gc = wv * 32 + n * 16 + r16;
                if (gc < N) C[(size_t)gr * N + gc] = acc[m][n][r] + bias[gc];
            }
        }
    }
}

// ---------------------------------------------------------------- alar via MFMA
// C[M,32] = X[M,K] @ Vt[32,K]^T; col r16 (n=0) -> al[gr*H+r16], n=1 -> ar[gr*H+r16] (r16<H)
template <int H>
__global__ __launch_bounds__(256) void alar3_k(const unsigned short* __restrict__ X,
                                               const unsigned short* __restrict__ Vt,
                                               float* __restrict__ al,
                                               float* __restrict__ ar,
                                               int M, int K) {
    __shared__ unsigned short Xs[128 * 40];
    __shared__ unsigned short Vs[32 * 40];
    const int tid  = threadIdx.x;
    const int lane = tid & 63;
    const int wv   = tid >> 6;
    const int r16  = lane & 15, kg = lane >> 4;
    const int bm   = blockIdx.x * 128;
    const bf16x8 zero8 = (bf16x8){0,0,0,0,0,0,0,0};

    f32x4 acc[2][2];
    #pragma unroll
    for (int m = 0; m < 2; ++m)
        #pragma unroll
        for (int n = 0; n < 2; ++n) acc[m][n] = (f32x4){0.f, 0.f, 0.f, 0.f};

    for (int k0 = 0; k0 < K; k0 += 32) {
        #pragma unroll
        for (int i = 0; i < 2; ++i) {           // X tile: 128 rows x 4 chunks
            int idx = tid + i * 256;
            int r = idx >> 2, c = idx & 3;
            int gr = bm + r;
            bf16x8 v = zero8;
            if (gr < M) v = *(const bf16x8*)(X + (size_t)gr * K + k0 + c * 8);
            *(bf16x8*)((char*)Xs + r * 80 + c * 16) = v;
        }
        if (tid < 128) {                        // Vt tile: 32 rows x 4 chunks
            int r = tid >> 2, c = tid & 3;
            *(bf16x8*)((char*)Vs + r * 80 + c * 16) =
                *(const bf16x8*)(Vt + (size_t)r * K + k0 + c * 8);
        }
        __syncthreads();
        bf16x8 fa[2], fb[2];
        #pragma unroll
        for (int m = 0; m < 2; ++m)
            fa[m] = *(const bf16x8*)((const char*)Xs + (wv * 32 + m * 16 + r16) * 80 + kg * 16);
        #pragma unroll
        for (int n = 0; n < 2; ++n)
            fb[n] = *(const bf16x8*)((const char*)Vs + (n * 16 + r16) * 80 + kg * 16);
        #pragma unroll
        for (int m = 0; m < 2; ++m)
            #pragma unroll
            for (int n = 0; n < 2; ++n)
                acc[m][n] = __builtin_amdgcn_mfma_f32_16x16x32_bf16(fa[m], fb[n], acc[m][n], 0, 0, 0);
        __syncthreads();
    }
    if (r16 < H) {
        #pragma unroll
        for (int m = 0; m < 2; ++m) {
            #pragma unroll
            for (int r = 0; r < 4; ++r) {
                int gr = bm + wv * 32 + m * 16 + kg * 4 + r;
                if (gr >= M) continue;
                al[(size_t)gr * H + r16] = acc[m][0][r];
                ar[(size_t)gr * H + r16] = acc[m][1][r];
            }
        }
    }
}

// ---------------------------------------------------------------- edge softmax -> alpha[e,h]
template <int H, int HP, int LOG2HP>
__global__ __launch_bounds__(256) void attn_alpha_k(const int* __restrict__ rowptr,
                                                    const int* __restrict__ csr_src,
                                                    const float* __restrict__ al,
                                                    const float* __restrict__ ar,
                                                    float* __restrict__ alpha) {
    const int NSLOT = 64 / HP;
    int wid  = threadIdx.x >> 6;
    int lane = threadIdx.x & 63;
    int n = blockIdx.x * 4 + wid;
    if (n >= NN) return;
    int h    = lane & (HP - 1);
    int slot = lane >> LOG2HP;
    bool hv = (h < H);
    int beg = rowptr[n], end = rowptr[n + 1];
    float ard = hv ? ar[n * H + h] : 0.f;

    float m = -1e30f, s = 0.f;
    for (int e = beg + slot; e < end; e += NSLOT) {
        int src = csr_src[e];
        float lg = -1e30f;
        if (hv) {
            lg = al[src * H + h] + ard;
            lg = (lg > 0.f) ? lg : 0.2f * lg;
        }
        float mn = fmaxf(m, lg);
        s = s * __expf(m - mn) + (hv ? __expf(lg - mn) : 0.f);
        m = mn;
    }
    #pragma unroll
    for (int off = HP; off < 64; off <<= 1) {
        float mo = __shfl_xor(m, off);
        float so = __shfl_xor(s, off);
        float mn = fmaxf(m, mo);
        s = s * __expf(m - mn) + so * __expf(mo - mn);
        m = mn;
    }
    if (hv) {
        float inv = 1.f / s;
        for (int e = beg + slot; e < end; e += NSLOT) {
            int src = csr_src[e];
            float lg = al[src * H + h] + ard;
            lg = (lg > 0.f) ? lg : 0.2f * lg;
            alpha[(size_t)e * H + h] = __expf(lg - m) * inv;
        }
    }
}

// ---------------------------------------------------------------- gather+skip+elu (layer2)
// Wave per node: 64 lanes x ushort4 (4 channels), 8-deep unroll.
__global__ __launch_bounds__(256) void gather_concat2_k(const int* __restrict__ rowptr,
                                                        const int* __restrict__ csr_src,
                                                        const unsigned short* __restrict__ hfeat,
                                                        const float* __restrict__ alpha,
                                                        const float* __restrict__ bias,
                                                        float* __restrict__ hidden,
                                                        unsigned short* __restrict__ hiddenb) {
    int wid = threadIdx.x >> 6, lane = threadIdx.x & 63;
    int n = blockIdx.x * 4 + wid;
    int hh = lane >> 4;                    // head of channels [lane*4, lane*4+4)
    int beg = rowptr[n], end = rowptr[n + 1];
    float a0c = 0.f, a1c = 0.f, a2c = 0.f, a3c = 0.f;
    int e = beg;
    for (; e + 8 <= end; e += 8) {
        int s_[8];
        float w_[8];
        ushort4 u_[8];
        #pragma unroll
        for (int j = 0; j < 8; ++j) s_[j] = csr_src[e + j];
        #pragma unroll
        for (int j = 0; j < 8; ++j) w_[j] = alpha[(size_t)(e + j) * 4 + hh];
        #pragma unroll
        for (int j = 0; j < 8; ++j)
            u_[j] = *(const ushort4*)(hfeat + (size_t)s_[j] * 512 + lane * 4);
        #pragma unroll
        for (int j = 0; j < 8; ++j) {
            a0c += w_[j] * bf2f(u_[j].x);
            a1c += w_[j] * bf2f(u_[j].y);
            a2c += w_[j] * bf2f(u_[j].z);
            a3c += w_[j] * bf2f(u_[j].w);
        }
    }
    for (; e < end; ++e) {
        int s = csr_src[e];
        float w = alpha[(size_t)e * 4 + hh];
        ushort4 u = *(const ushort4*)(hfeat + (size_t)s * 512 + lane * 4);
        a0c += w * bf2f(u.x); a1c += w * bf2f(u.y);
        a2c += w * bf2f(u.z); a3c += w * bf2f(u.w);
    }
    ushort4 sk = *(const ushort4*)(hfeat + (size_t)n * 512 + 256 + lane * 4);
    const float* bp = bias + lane * 4;
    float v0 = a0c + bf2f(sk.x) + bp[0];
    float v1 = a1c + bf2f(sk.y) + bp[1];
    float v2 = a2c + bf2f(sk.z) + bp[2];
    float v3 = a3c + bf2f(sk.w) + bp[3];
    v0 = (v0 > 0.f) ? v0 : expm1f(v0);
    v1 = (v1 > 0.f) ? v1 : expm1f(v1);
    v2 = (v2 > 0.f) ? v2 : expm1f(v2);
    v3 = (v3 > 0.f) ? v3 : expm1f(v3);
    float4 rf; rf.x = v0; rf.y = v1; rf.z = v2; rf.w = v3;
    *(float4*)(hidden + (size_t)n * 256 + lane * 4) = rf;
    ushort4 rb; rb.x = f2bf(v0); rb.y = f2bf(v1); rb.z = f2bf(v2); rb.w = f2bf(v3);
    *(ushort4*)(hiddenb + (size_t)n * 256 + lane * 4) = rb;
}

// ---------------------------------------------------------------- layer-1 aggregate gather
__global__ __launch_bounds__(256) void gather_agg1_k(const int* __restrict__ rowptr,
                                                     const int* __restrict__ csr_src,
                                                     const unsigned short* __restrict__ xb,
                                                     const float* __restrict__ alpha,
                                                     unsigned short* __restrict__ agg) {
    int wid = threadIdx.x >> 6, lane = threadIdx.x & 63;
    int n = blockIdx.x * 4 + wid;
    int beg = rowptr[n], end = rowptr[n + 1];
    float acc0 = 0.f, acc1 = 0.f, acc2 = 0.f, acc3 = 0.f;
    int e = beg;
    for (; e + 4 <= end; e += 4) {
        int s0 = csr_src[e], s1 = csr_src[e + 1], s2 = csr_src[e + 2], s3 = csr_src[e + 3];
        float x0 = bf2f(xb[(size_t)s0 * 64 + lane]);
        float x1 = bf2f(xb[(size_t)s1 * 64 + lane]);
        float x2 = bf2f(xb[(size_t)s2 * 64 + lane]);
        float x3 = bf2f(xb[(size_t)s3 * 64 + lane]);
        const float* a = &alpha[(size_t)e * 4];
        acc0 += a[0] * x0 + a[4] * x1 + a[8]  * x2 + a[12] * x3;
        acc1 += a[1] * x0 + a[5] * x1 + a[9]  * x2 + a[13] * x3;
        acc2 += a[2] * x0 + a[6] * x1 + a[10] * x2 + a[14] * x3;
        acc3 += a[3] * x0 + a[7] * x1 + a[11] * x2 + a[15] * x3;
    }
    for (; e < end; ++e) {
        int s = csr_src[e];
        float x = bf2f(xb[(size_t)s * 64 + lane]);
        const float* a = &alpha[(size_t)e * 4];
        acc0 += a[0] * x; acc1 += a[1] * x; acc2 += a[2] * x; acc3 += a[3] * x;
    }
    size_t o = (size_t)n * 320;
    agg[o + 0 * 64 + lane] = f2bf(acc0);
    agg[o + 1 * 64 + lane] = f2bf(acc1);
    agg[o + 2 * 64 + lane] = f2bf(acc2);
    agg[o + 3 * 64 + lane] = f2bf(acc3);
    agg[o + 256 + lane]    = xb[(size_t)n * 64 + lane];   // skip-path copy
}

// ---------------------------------------------------------------- layer-3 aggregate gather (chunked)
// Wave per node: 64 lanes x ushort4; 24 accumulators; unroll-4 edge loads.
__global__ __launch_bounds__(256) void gather_agg3_k(const int* __restrict__ rowptr,
                                                     const int* __restrict__ csr_src,
                                                     const unsigned short* __restrict__ hb,
                                                     const float* __restrict__ alpha,
                                                     unsigned short* __restrict__ agg,
                                                     int base) {
    int wid = threadIdx.x >> 6, lane = threadIdx.x & 63;
    int li  = blockIdx.x * 4 + wid;        // local node index within chunk
    int n   = base + li;
    int beg = rowptr[n], end = rowptr[n + 1];
    float acc[6][4];
    #pragma unroll
    for (int h = 0; h < 6; ++h)
        #pragma unroll
        for (int c = 0; c < 4; ++c) acc[h][c] = 0.f;

    int e = beg;
    for (; e + 4 <= end; e += 4) {
        int s_[4];
        ushort4 u_[4];
        #pragma unroll
        for (int j = 0; j < 4; ++j) s_[j] = csr_src[e + j];
        #pragma unroll
        for (int j = 0; j < 4; ++j)
            u_[j] = *(const ushort4*)(hb + (size_t)s_[j] * 256 + lane * 4);
        #pragma unroll
        for (int j = 0; j < 4; ++j) {
            const float* a = &alpha[(size_t)(e + j) * 6];
            float f0 = bf2f(u_[j].x), f1 = bf2f(u_[j].y);
            float f2 = bf2f(u_[j].z), f3 = bf2f(u_[j].w);
            #pragma unroll
            for (int h = 0; h < 6; ++h) {
                float w = a[h];
                acc[h][0] += w * f0; acc[h][1] += w * f1;
                acc[h][2] += w * f2; acc[h][3] += w * f3;
            }
        }
    }
    for (; e < end; ++e) {
        int s = csr_src[e];
        const float* a = &alpha[(size_t)e * 6];
        ushort4 u = *(const ushort4*)(hb + (size_t)s * 256 + lane * 4);
        float f0 = bf2f(u.x), f1 = bf2f(u.y), f2 = bf2f(u.z), f3 = bf2f(u.w);
        #pragma unroll
        for (int h = 0; h < 6; ++h) {
            float w = a[h];
            acc[h][0] += w * f0; acc[h][1] += w * f1;
            acc[h][2] += w * f2; acc[h][3] += w * f3;
        }
    }
    size_t o = (size_t)li * 1792;
    #pragma unroll
    for (int h = 0; h < 6; ++h) {
        ushort4 r;
        r.x = f2bf(acc[h][0]); r.y = f2bf(acc[h][1]);
        r.z = f2bf(acc[h][2]); r.w = f2bf(acc[h][3]);
        *(ushort4*)(agg + o + h * 256 + lane * 4) = r;
    }
    *(ushort4*)(agg + o + 1536 + lane * 4) =
        *(const ushort4*)(hb + (size_t)n * 256 + lane * 4);   // skip-path copy
}

// ---------------------------------------------------------------- launch
extern "C" void kernel_launch(void* const* d_in, const int* in_sizes, int n_in,
                              void* d_out, int out_size, void* d_ws, size_t ws_size,
                              hipStream_t stream) {
    const float* x   = (const float*)d_in[0];
    const int*   ei  = (const int*)d_in[1];
    const float* W1  = (const float*)d_in[2];
    const float* a1s = (const float*)d_in[3];
    const float* a1d = (const float*)d_in[4];
    const float* b1  = (const float*)d_in[5];
    const float* Wl1 = (const float*)d_in[6];
    const float* bl1 = (const float*)d_in[7];
    const float* W2  = (const float*)d_in[8];
    const float* a2s = (const float*)d_in[9];
    const float* a2d = (const float*)d_in[10];
    const float* b2  = (const float*)d_in[11];
    const float* Wl2 = (const float*)d_in[12];
    const float* bl2 = (const float*)d_in[13];
    const float* W3  = (const float*)d_in[14];
    const float* a3s = (const float*)d_in[15];
    const float* a3d = (const float*)d_in[16];
    const float* b3  = (const float*)d_in[17];
    const float* Wl3 = (const float*)d_in[18];
    const float* bl3 = (const float*)d_in[19];

    float* out    = (float*)d_out;                 // [40000,121]
    float* hidden = out + (size_t)NN * 121;        // [40000,256]

    // workspace layout (~135 MB; agg3 aliases dead layer-1/2 buffers)
    char* ws = (char*)d_ws;
    size_t off = 0;
    auto alloc = [&](size_t bytes) { size_t o = off; off = (off + bytes + 255) & ~(size_t)255; return o; };
    int*   counts    = (int*)(ws + alloc((size_t)NN * 4));
    int*   rowptr    = (int*)(ws + alloc((size_t)(NN + 1) * 4));
    int*   blocksums = (int*)(ws + alloc(256 * 4));
    int*   csr_src   = (int*)(ws + alloc((size_t)ETOT * 4));
    float* al        = (float*)(ws + alloc((size_t)NN * 6 * 4));
    float* ar        = (float*)(ws + alloc((size_t)NN * 6 * 4));
    float* alpha     = (float*)(ws + alloc((size_t)ETOT * 6 * 4));
    unsigned short* hiddenb = (unsigned short*)(ws + alloc((size_t)NN * 256 * 2));
    unsigned short* w2c     = (unsigned short*)(ws + alloc((size_t)512 * 256 * 2));
    unsigned short* bt1     = (unsigned short*)(ws + alloc((size_t)256 * 320 * 2));
    unsigned short* bt3     = (unsigned short*)(ws + alloc((size_t)121 * 1792 * 2));
    unsigned short* vt1     = (unsigned short*)(ws + alloc((size_t)32 * 64 * 2));
    unsigned short* vt2     = (unsigned short*)(ws + alloc((size_t)32 * 256 * 2));
    unsigned short* vt3     = (unsigned short*)(ws + alloc((size_t)32 * 256 * 2));
    float* bias1s  = (float*)(ws + alloc(256 * 4));
    float* bias2s  = (float*)(ws + alloc(256 * 4));
    float* bias3s  = (float*)(ws + alloc(128 * 4));
    // UNION region: layers 1-2 use {hfeat2b[N,512], xb, h1b, agg1}; layer 3 reuses as agg3 (20000x1792)
    size_t uoff = alloc((size_t)NN * 512 * 2 + (size_t)NN * 64 * 2 +
                        (size_t)NN * 256 * 2 + (size_t)NN * 320 * 2 + 1024);
    unsigned short* hfeat2b = (unsigned short*)(ws + uoff);
    unsigned short* xb      = hfeat2b + (size_t)NN * 512;
    unsigned short* h1b     = xb + (size_t)NN * 64;
    unsigned short* agg1    = h1b + (size_t)NN * 256;
    unsigned short* agg3    = hfeat2b;   // alias: 20000*1792 = NN*896 shorts <= union size

    const int eblocks = (ETOT + 255) / 256;
    const int ablocks = NN / 4;        // 10000
    const int mg  = (NN + 127) / 128;  // 313

    // ---- prep (reads inputs only)
    xprep_k<<<(NN * 64 + 255) / 256, 256, 0, stream>>>(x, xb);
    w1prep_k<<<256, 256, 0, stream>>>(W1, Wl1, bt1);
    w2prep_k<<<512, 256, 0, stream>>>(W2, Wl2, w2c);
    w3prep_k<<<121, 256, 0, stream>>>(W3, Wl3, bt3);
    attvec2_k<<<(64 * 32 + 255) / 256, 256, 0, stream>>>(W1, a1s, a1d, vt1, 50, 64, 4, 64);
    attvec2_k<<<(256 * 32 + 255) / 256, 256, 0, stream>>>(W2, a2s, a2d, vt2, 256, 256, 4, 64);
    attvec2_k<<<(256 * 32 + 255) / 256, 256, 0, stream>>>(W3, a3s, a3d, vt3, 256, 256, 6, 121);
    biases_k<<<1, 256, 0, stream>>>(b1, bl1, b2, bl2, b3, bl3, bias1s, bias2s, bias3s);

    // ---- CSR build
    hipMemsetAsync(counts, 0, (size_t)NN * 4, stream);
    count_k<<<eblocks, 256, 0, stream>>>(ei, counts);
    scan_k<<<NBLK, 256, 0, stream>>>(counts, rowptr, blocksums, NN);
    scan_k<<<1, 256, 0, stream>>>(blocksums, blocksums, nullptr, NBLK);
    add_off_k<<<NBLK, 256, 0, stream>>>(rowptr, blocksums);
    hipMemsetAsync(counts, 0, (size_t)NN * 4, stream);  // reuse as cursor
    scatter_k<<<eblocks, 256, 0, stream>>>(ei, rowptr, counts, csr_src);

    // ---- Layer 1: aggregate-first. h1b = elu(agg1 @ bt1 + b1 + bl1)
    alar3_k<4><<<mg, 256, 0, stream>>>(xb, vt1, al, ar, NN, 64);
    attn_alpha_k<4, 4, 2><<<ablocks, 256, 0, stream>>>(rowptr, csr_src, al, ar, alpha);
    gather_agg1_k<<<ablocks, 256, 0, stream>>>(rowptr, csr_src, xb, alpha, agg1);
    gemm_bf16_k<6><<<dim3(2, mg), 256, 0, stream>>>(agg1, bt1, bias1s, nullptr, h1b, NN, 256, 320);

    // ---- Layer 2: one combined GEMM (features|skip), MFMA alar, fused gather epilogue
    gemm_bf16_k<3><<<dim3(4, mg), 256, 0, stream>>>(h1b, w2c, nullptr, nullptr, hfeat2b, NN, 512, 256);
    alar3_k<4><<<mg, 256, 0, stream>>>(h1b, vt2, al, ar, NN, 256);
    attn_alpha_k<4, 4, 2><<<ablocks, 256, 0, stream>>>(rowptr, csr_src, al, ar, alpha);
    gather_concat2_k<<<ablocks, 256, 0, stream>>>(rowptr, csr_src, hfeat2b, alpha, bias2s, hidden, hiddenb);

    // ---- Layer 3: aggregate-first, 2 chunks of 20000 (agg3 aliases dead buffers)
    alar3_k<6><<<mg, 256, 0, stream>>>(hiddenb, vt3, al, ar, NN, 256);
    attn_alpha_k<6, 8, 3><<<ablocks, 256, 0, stream>>>(rowptr, csr_src, al, ar, alpha);
    for (int c = 0; c < 2; ++c) {
        int base = c * 20000;
        gather_agg3_k<<<5000, 256, 0, stream>>>(rowptr, csr_src, hiddenb, alpha, agg3, base);
        gemm_skinny_k<<<625, 256, 0, stream>>>(agg3, bt3, bias3s,
                                               out + (size_t)base * 121, 20000, 121, 1792);
    }
}

// Round 13
// 539.669 us; speedup vs baseline: 1.0358x; 1.0358x over previous
//
#include <hip/hip_runtime.h>
#include <math.h>

#define NN   40000
#define EE   640000
#define ETOT (EE + NN)          // 680000 edges incl self-loops
#define NBLK ((NN + 255) / 256) // 157

typedef short bf16x8 __attribute__((ext_vector_type(8)));
typedef float f32x4  __attribute__((ext_vector_type(4)));

__device__ __forceinline__ unsigned short f2bf(float f) {
    unsigned int u = __float_as_uint(f);
    u += 0x7fff + ((u >> 16) & 1);          // RNE
    return (unsigned short)(u >> 16);
}
__device__ __forceinline__ float bf2f(unsigned short h) {
    return __uint_as_float(((unsigned int)h) << 16);
}

// ---------------------------------------------------------------- CSR build
__global__ void count_k(const int* __restrict__ ei, int* __restrict__ counts) {
    int e = blockIdx.x * 256 + threadIdx.x;
    if (e >= ETOT) return;
    int d = (e < EE) ? ei[EE + e] : (e - EE);
    atomicAdd(&counts[d], 1);
}

__global__ __launch_bounds__(256) void scan_k(const int* __restrict__ in,
                                              int* __restrict__ out,
                                              int* __restrict__ sums, int n) {
    __shared__ int tmp[256];
    int i = blockIdx.x * 256 + threadIdx.x;
    int v = (i < n) ? in[i] : 0;
    tmp[threadIdx.x] = v;
    __syncthreads();
    #pragma unroll
    for (int off = 1; off < 256; off <<= 1) {
        int t = (threadIdx.x >= off) ? tmp[threadIdx.x - off] : 0;
        __syncthreads();
        tmp[threadIdx.x] += t;
        __syncthreads();
    }
    if (i < n) out[i] = tmp[threadIdx.x] - v;   // exclusive
    if (sums != nullptr && threadIdx.x == 255) sums[blockIdx.x] = tmp[255];
}

__global__ void add_off_k(int* __restrict__ data, const int* __restrict__ offs) {
    int i = blockIdx.x * 256 + threadIdx.x;
    if (i < NN) data[i] += offs[blockIdx.x];
    if (blockIdx.x == 0 && threadIdx.x == 0) data[NN] = ETOT;
}

__global__ void scatter_k(const int* __restrict__ ei, const int* __restrict__ rowptr,
                          int* __restrict__ cursor, int* __restrict__ csr_src) {
    int e = blockIdx.x * 256 + threadIdx.x;
    if (e >= ETOT) return;
    int s, d;
    if (e < EE) { s = ei[e]; d = ei[EE + e]; } else { s = d = e - EE; }
    int pos = rowptr[d] + atomicAdd(&cursor[d], 1);
    csr_src[pos] = s;
}

// ---------------------------------------------------------------- prep kernels
// x [NN][50] f32 -> xb [NN][64] bf16 (zero pad)
__global__ __launch_bounds__(256) void xprep_k(const float* __restrict__ x,
                                               unsigned short* __restrict__ xb) {
    int idx = blockIdx.x * 256 + threadIdx.x;   // NN*64 total
    if (idx >= NN * 64) return;
    int m = idx >> 6, k = idx & 63;
    xb[idx] = (k < 50) ? f2bf(x[(size_t)m * 50 + k]) : (unsigned short)0;
}

// layer-1 combined B: bt1[c][kk], kk<256: block-diag W1; kk in [256,320): Wl1
__global__ void w1prep_k(const float* __restrict__ W1, const float* __restrict__ Wl1,
                         unsigned short* __restrict__ bt) {
    int c = blockIdx.x;   // 0..255
    int hc = c >> 6;
    for (int kk = threadIdx.x; kk < 320; kk += blockDim.x) {
        float v = 0.f;
        if (kk < 256) {
            int h = kk >> 6, k = kk & 63;
            if (h == hc && k < 50) v = W1[(size_t)k * 256 + c];
        } else {
            int k = kk - 256;
            if (k < 50) v = Wl1[(size_t)k * 256 + c];
        }
        bt[(size_t)c * 320 + kk] = f2bf(v);
    }
}

// layer-2 combined B: w2c[c][k], c<256: W2 col c; c in [256,512): Wl2 col c-256
__global__ void w2prep_k(const float* __restrict__ W2, const float* __restrict__ Wl2,
                         unsigned short* __restrict__ wt) {
    int c = blockIdx.x;   // 0..511
    for (int k = threadIdx.x; k < 256; k += blockDim.x) {
        float v = (c < 256) ? W2[(size_t)k * 256 + c] : Wl2[(size_t)k * 256 + (c - 256)];
        wt[(size_t)c * 256 + k] = f2bf(v);
    }
}

// layer-3 combined B: bt3[c][kk], kk<1536: W3[k, h*121+c]/6; kk in [1536,1792): Wl3
__global__ void w3prep_k(const float* __restrict__ W3, const float* __restrict__ Wl3,
                         unsigned short* __restrict__ bt) {
    int c = blockIdx.x;   // 0..120
    for (int kk = threadIdx.x; kk < 1792; kk += blockDim.x) {
        float v;
        if (kk < 1536) {
            int h = kk >> 8, k = kk & 255;
            v = W3[(size_t)k * 726 + h * 121 + c] * (1.f / 6.f);
        } else {
            int k = kk - 1536;
            v = Wl3[(size_t)k * 121 + c];
        }
        bt[(size_t)c * 1792 + kk] = f2bf(v);
    }
}

// attention projection matrix, bf16: Vt[j][k], j<16: va_j (j<H), j>=16: vb_{j-16}
__global__ void attvec2_k(const float* __restrict__ W, const float* __restrict__ as_,
                          const float* __restrict__ ad, unsigned short* __restrict__ Vt,
                          int Kreal, int Kpad, int H, int OC) {
    int idx = blockIdx.x * 256 + threadIdx.x;   // Kpad*32
    if (idx >= Kpad * 32) return;
    int k = idx >> 5, j = idx & 31;
    int h = j & 15;
    float s = 0.f;
    if (k < Kreal && h < H) {
        const float* wrow = W + (size_t)k * (H * OC) + h * OC;
        const float* av = (j < 16) ? as_ : ad;
        for (int c = 0; c < OC; ++c) s += wrow[c] * av[h * OC + c];
    }
    Vt[(size_t)j * Kpad + k] = f2bf(s);
}

// merged bias sums: o1=b1+bl1 [256], o2=b2+bl2 [256], o3=b3+bl3 [121]
__global__ void biases_k(const float* __restrict__ b1, const float* __restrict__ bl1,
                         const float* __restrict__ b2, const float* __restrict__ bl2,
                         const float* __restrict__ b3, const float* __restrict__ bl3,
                         float* __restrict__ o1, float* __restrict__ o2,
                         float* __restrict__ o3) {
    int i = threadIdx.x;
    if (i < 256) { o1[i] = b1[i] + bl1[i]; o2[i] = b2[i] + bl2[i]; }
    if (i < 121) o3[i] = b3[i] + bl3[i];
}

// ---------------------------------------------------------------- bf16 MFMA GEMM (128x128 tile)
// C[M,N] = A[M,K] @ Bt[N,K]^T.  A,Bt bf16 row-major; K % 32 == 0.
// MODE 3: Cb=AB bf16 | MODE 6: Cb=elu(AB+bias) bf16
template <int MODE>
__global__ __launch_bounds__(256, 4) void gemm_bf16_k(const unsigned short* __restrict__ A,
                                                      const unsigned short* __restrict__ Bt,
                                                      const float* __restrict__ bias,
                                                      float* __restrict__ C,
                                                      unsigned short* __restrict__ Cb,
                                                      int M, int N, int K) {
    // 80B row stride (40 shorts): ds_read_b128 start banks spread evenly
    __shared__ unsigned short As[128 * 40];
    __shared__ unsigned short Bs[128 * 40];
    const int tid  = threadIdx.x;
    const int lane = tid & 63;
    const int wv   = tid >> 6;
    const int wm   = wv >> 1, wn = wv & 1;
    const int r16  = lane & 15, kg = lane >> 4;
    const int bm   = blockIdx.y * 128, bn = blockIdx.x * 128;

    f32x4 acc[4][4];
    #pragma unroll
    for (int m = 0; m < 4; ++m)
        #pragma unroll
        for (int n = 0; n < 4; ++n) acc[m][n] = (f32x4){0.f, 0.f, 0.f, 0.f};

    const bf16x8 zero8 = (bf16x8){0,0,0,0,0,0,0,0};
    for (int k0 = 0; k0 < K; k0 += 32) {
        #pragma unroll
        for (int i = 0; i < 2; ++i) {
            int idx = tid + i * 256;            // 0..511
            int r = idx >> 2, c = idx & 3;      // row, 16B chunk
            int gr = bm + r;
            bf16x8 v = zero8;
            if (gr < M) v = *(const bf16x8*)(A + (size_t)gr * K + k0 + c * 8);
            *(bf16x8*)((char*)As + r * 80 + c * 16) = v;
            int gn = bn + r;
            bf16x8 w = zero8;
            if (gn < N) w = *(const bf16x8*)(Bt + (size_t)gn * K + k0 + c * 8);
            *(bf16x8*)((char*)Bs + r * 80 + c * 16) = w;
        }
        __syncthreads();
        bf16x8 fa[4], fb[4];
        #pragma unroll
        for (int m = 0; m < 4; ++m)
            fa[m] = *(const bf16x8*)((const char*)As + (wm * 64 + m * 16 + r16) * 80 + kg * 16);
        #pragma unroll
        for (int n = 0; n < 4; ++n)
            fb[n] = *(const bf16x8*)((const char*)Bs + (wn * 64 + n * 16 + r16) * 80 + kg * 16);
        #pragma unroll
        for (int m = 0; m < 4; ++m)
            #pragma unroll
            for (int n = 0; n < 4; ++n)
                acc[m][n] = __builtin_amdgcn_mfma_f32_16x16x32_bf16(fa[m], fb[n], acc[m][n], 0, 0, 0);
        __syncthreads();
    }
    #pragma unroll
    for (int m = 0; m < 4; ++m) {
        #pragma unroll
        for (int r = 0; r < 4; ++r) {
            int gr = bm + wm * 64 + m * 16 + kg * 4 + r;
            if (gr >= M) continue;
            #pragma unroll
            for (int n = 0; n < 4; ++n) {
                int gc = bn + wn * 64 + n * 16 + r16;
                if (gc >= N) continue;
                size_t o = (size_t)gr * N + gc;
                float v = acc[m][n][r];
                if (MODE == 3) {
                    Cb[o] = f2bf(v);
                } else if (MODE == 6) {
                    float w = v + bias[gc];
                    w = (w > 0.f) ? w : expm1f(w);
                    Cb[o] = f2bf(w);
                }
            }
        }
    }
}

// ---------------------------------------------------------------- skinny GEMM (32xN tile, N<=128)
__global__ __launch_bounds__(256) void gemm_skinny_k(const unsigned short* __restrict__ A,
                                                     const unsigned short* __restrict__ Bt,
                                                     const float* __restrict__ bias,
                                                     float* __restrict__ C,
                                                     int M, int N, int K) {
    __shared__ unsigned short As[32 * 40];
    __shared__ unsigned short Bs[128 * 40];
    const int tid  = threadIdx.x;
    const int lane = tid & 63;
    const int wv   = tid >> 6;
    const int r16  = lane & 15, kg = lane >> 4;
    const int bm   = blockIdx.x * 32;

    f32x4 acc[2][2];
    #pragma unroll
    for (int m = 0; m < 2; ++m)
        #pragma unroll
        for (int n = 0; n < 2; ++n) acc[m][n] = (f32x4){0.f, 0.f, 0.f, 0.f};

    const bf16x8 zero8 = (bf16x8){0,0,0,0,0,0,0,0};
    for (int k0 = 0; k0 < K; k0 += 32) {
        if (tid < 128) {                        // A tile: 32 rows x 4 chunks
            int r = tid >> 2, c = tid & 3;
            *(bf16x8*)((char*)As + r * 80 + c * 16) =
                *(const bf16x8*)(A + (size_t)(bm + r) * K + k0 + c * 8);
        }
        #pragma unroll
        for (int i = 0; i < 2; ++i) {           // B tile: 128 rows x 4 chunks
            int idx = tid + i * 256;
            int r = idx >> 2, c = idx & 3;
            bf16x8 w = zero8;
            if (r < N) w = *(const bf16x8*)(Bt + (size_t)r * K + k0 + c * 8);
            *(bf16x8*)((char*)Bs + r * 80 + c * 16) = w;
        }
        __syncthreads();
        bf16x8 fa[2], fb[2];
        #pragma unroll
        for (int m = 0; m < 2; ++m)
            fa[m] = *(const bf16x8*)((const char*)As + (m * 16 + r16) * 80 + kg * 16);
        #pragma unroll
        for (int n = 0; n < 2; ++n)
            fb[n] = *(const bf16x8*)((const char*)Bs + (wv * 32 + n * 16 + r16) * 80 + kg * 16);
        #pragma unroll
        for (int m = 0; m < 2; ++m)
            #pragma unroll
            for (int n = 0; n < 2; ++n)
                acc[m][n] = __builtin_amdgcn_mfma_f32_16x16x32_bf16(fa[m], fb[n], acc[m][n], 0, 0, 0);
        __syncthreads();
    }
    #pragma unroll
    for (int m = 0; m < 2; ++m) {
        #pragma unroll
        for (int r = 0; r < 4; ++r) {
            int gr = bm + m * 16 + kg * 4 + r;
            #pragma unroll
            for (int n = 0; n < 2; ++n) {
                int gc = wv * 32 + n * 16 + r16;
                if (gc < N) C[(size_t)gr * N + gc] = acc[m][n][r] + bias[gc];
            }
        }
    }
}

// ---------------------------------------------------------------- alar via MFMA
// C[M,32] = X[M,K] @ Vt[32,K]^T; col r16 (n=0) -> al[gr*H+r16], n=1 -> ar[gr*H+r16] (r16<H)
template <int H>
__global__ __launch_bounds__(256) void alar3_k(const unsigned short* __restrict__ X,
                                               const unsigned short* __restrict__ Vt,
                                               float* __restrict__ al,
                                               float* __restrict__ ar,
                                               int M, int K) {
    __shared__ unsigned short Xs[128 * 40];
    __shared__ unsigned short Vs[32 * 40];
    const int tid  = threadIdx.x;
    const int lane = tid & 63;
    const int wv   = tid >> 6;
    const int r16  = lane & 15, kg = lane >> 4;
    const int bm   = blockIdx.x * 128;
    const bf16x8 zero8 = (bf16x8){0,0,0,0,0,0,0,0};

    f32x4 acc[2][2];
    #pragma unroll
    for (int m = 0; m < 2; ++m)
        #pragma unroll
        for (int n = 0; n < 2; ++n) acc[m][n] = (f32x4){0.f, 0.f, 0.f, 0.f};

    for (int k0 = 0; k0 < K; k0 += 32) {
        #pragma unroll
        for (int i = 0; i < 2; ++i) {           // X tile: 128 rows x 4 chunks
            int idx = tid + i * 256;
            int r = idx >> 2, c = idx & 3;
            int gr = bm + r;
            bf16x8 v = zero8;
            if (gr < M) v = *(const bf16x8*)(X + (size_t)gr * K + k0 + c * 8);
            *(bf16x8*)((char*)Xs + r * 80 + c * 16) = v;
        }
        if (tid < 128) {                        // Vt tile: 32 rows x 4 chunks
            int r = tid >> 2, c = tid & 3;
            *(bf16x8*)((char*)Vs + r * 80 + c * 16) =
                *(const bf16x8*)(Vt + (size_t)r * K + k0 + c * 8);
        }
        __syncthreads();
        bf16x8 fa[2], fb[2];
        #pragma unroll
        for (int m = 0; m < 2; ++m)
            fa[m] = *(const bf16x8*)((const char*)Xs + (wv * 32 + m * 16 + r16) * 80 + kg * 16);
        #pragma unroll
        for (int n = 0; n < 2; ++n)
            fb[n] = *(const bf16x8*)((const char*)Vs + (n * 16 + r16) * 80 + kg * 16);
        #pragma unroll
        for (int m = 0; m < 2; ++m)
            #pragma unroll
            for (int n = 0; n < 2; ++n)
                acc[m][n] = __builtin_amdgcn_mfma_f32_16x16x32_bf16(fa[m], fb[n], acc[m][n], 0, 0, 0);
        __syncthreads();
    }
    if (r16 < H) {
        #pragma unroll
        for (int m = 0; m < 2; ++m) {
            #pragma unroll
            for (int r = 0; r < 4; ++r) {
                int gr = bm + wv * 32 + m * 16 + kg * 4 + r;
                if (gr >= M) continue;
                al[(size_t)gr * H + r16] = acc[m][0][r];
                ar[(size_t)gr * H + r16] = acc[m][1][r];
            }
        }
    }
}

// ---------------------------------------------------------------- edge softmax -> alpha[e,h]
template <int H, int HP, int LOG2HP>
__global__ __launch_bounds__(256) void attn_alpha_k(const int* __restrict__ rowptr,
                                                    const int* __restrict__ csr_src,
                                                    const float* __restrict__ al,
                                                    const float* __restrict__ ar,
                                                    float* __restrict__ alpha) {
    const int NSLOT = 64 / HP;
    int wid  = threadIdx.x >> 6;
    int lane = threadIdx.x & 63;
    int n = blockIdx.x * 4 + wid;
    if (n >= NN) return;
    int h    = lane & (HP - 1);
    int slot = lane >> LOG2HP;
    bool hv = (h < H);
    int beg = rowptr[n], end = rowptr[n + 1];
    float ard = hv ? ar[n * H + h] : 0.f;

    float m = -1e30f, s = 0.f;
    for (int e = beg + slot; e < end; e += NSLOT) {
        int src = csr_src[e];
        float lg = -1e30f;
        if (hv) {
            lg = al[src * H + h] + ard;
            lg = (lg > 0.f) ? lg : 0.2f * lg;
        }
        float mn = fmaxf(m, lg);
        s = s * __expf(m - mn) + (hv ? __expf(lg - mn) : 0.f);
        m = mn;
    }
    #pragma unroll
    for (int off = HP; off < 64; off <<= 1) {
        float mo = __shfl_xor(m, off);
        float so = __shfl_xor(s, off);
        float mn = fmaxf(m, mo);
        s = s * __expf(m - mn) + so * __expf(mo - mn);
        m = mn;
    }
    if (hv) {
        float inv = 1.f / s;
        for (int e = beg + slot; e < end; e += NSLOT) {
            int src = csr_src[e];
            float lg = al[src * H + h] + ard;
            lg = (lg > 0.f) ? lg : 0.2f * lg;
            alpha[(size_t)e * H + h] = __expf(lg - m) * inv;
        }
    }
}

// ---------------------------------------------------------------- gather+skip+elu (layer2)
// Wave per node: 64 lanes x ushort4 (4 channels). hfeat [N][512]: cols 0-255 feat, 256-511 skip.
__global__ __launch_bounds__(256) void gather_concat2_k(const int* __restrict__ rowptr,
                                                        const int* __restrict__ csr_src,
                                                        const unsigned short* __restrict__ hfeat,
                                                        const float* __restrict__ alpha,
                                                        const float* __restrict__ bias,
                                                        float* __restrict__ hidden,
                                                        unsigned short* __restrict__ hiddenb) {
    int wid = threadIdx.x >> 6, lane = threadIdx.x & 63;
    int n = blockIdx.x * 4 + wid;
    int hh = lane >> 4;                    // head of channels [lane*4, lane*4+4)
    int beg = rowptr[n], end = rowptr[n + 1];
    float a0c = 0.f, a1c = 0.f, a2c = 0.f, a3c = 0.f;
    int e = beg;
    for (; e + 4 <= end; e += 4) {
        int s0 = csr_src[e], s1 = csr_src[e + 1], s2 = csr_src[e + 2], s3 = csr_src[e + 3];
        float w0 = alpha[(size_t)(e + 0) * 4 + hh];
        float w1 = alpha[(size_t)(e + 1) * 4 + hh];
        float w2 = alpha[(size_t)(e + 2) * 4 + hh];
        float w3 = alpha[(size_t)(e + 3) * 4 + hh];
        ushort4 u0 = *(const ushort4*)(hfeat + (size_t)s0 * 512 + lane * 4);
        ushort4 u1 = *(const ushort4*)(hfeat + (size_t)s1 * 512 + lane * 4);
        ushort4 u2 = *(const ushort4*)(hfeat + (size_t)s2 * 512 + lane * 4);
        ushort4 u3 = *(const ushort4*)(hfeat + (size_t)s3 * 512 + lane * 4);
        a0c += w0 * bf2f(u0.x) + w1 * bf2f(u1.x) + w2 * bf2f(u2.x) + w3 * bf2f(u3.x);
        a1c += w0 * bf2f(u0.y) + w1 * bf2f(u1.y) + w2 * bf2f(u2.y) + w3 * bf2f(u3.y);
        a2c += w0 * bf2f(u0.z) + w1 * bf2f(u1.z) + w2 * bf2f(u2.z) + w3 * bf2f(u3.z);
        a3c += w0 * bf2f(u0.w) + w1 * bf2f(u1.w) + w2 * bf2f(u2.w) + w3 * bf2f(u3.w);
    }
    for (; e < end; ++e) {
        int s = csr_src[e];
        float w = alpha[(size_t)e * 4 + hh];
        ushort4 u = *(const ushort4*)(hfeat + (size_t)s * 512 + lane * 4);
        a0c += w * bf2f(u.x); a1c += w * bf2f(u.y);
        a2c += w * bf2f(u.z); a3c += w * bf2f(u.w);
    }
    ushort4 sk = *(const ushort4*)(hfeat + (size_t)n * 512 + 256 + lane * 4);
    const float* bp = bias + lane * 4;
    float v0 = a0c + bf2f(sk.x) + bp[0];
    float v1 = a1c + bf2f(sk.y) + bp[1];
    float v2 = a2c + bf2f(sk.z) + bp[2];
    float v3 = a3c + bf2f(sk.w) + bp[3];
    v0 = (v0 > 0.f) ? v0 : expm1f(v0);
    v1 = (v1 > 0.f) ? v1 : expm1f(v1);
    v2 = (v2 > 0.f) ? v2 : expm1f(v2);
    v3 = (v3 > 0.f) ? v3 : expm1f(v3);
    float4 rf; rf.x = v0; rf.y = v1; rf.z = v2; rf.w = v3;
    *(float4*)(hidden + (size_t)n * 256 + lane * 4) = rf;
    ushort4 rb; rb.x = f2bf(v0); rb.y = f2bf(v1); rb.z = f2bf(v2); rb.w = f2bf(v3);
    *(ushort4*)(hiddenb + (size_t)n * 256 + lane * 4) = rb;
}

// ---------------------------------------------------------------- layer-1 aggregate gather
__global__ __launch_bounds__(256) void gather_agg1_k(const int* __restrict__ rowptr,
                                                     const int* __restrict__ csr_src,
                                                     const unsigned short* __restrict__ xb,
                                                     const float* __restrict__ alpha,
                                                     unsigned short* __restrict__ agg) {
    int wid = threadIdx.x >> 6, lane = threadIdx.x & 63;
    int n = blockIdx.x * 4 + wid;
    int beg = rowptr[n], end = rowptr[n + 1];
    float acc0 = 0.f, acc1 = 0.f, acc2 = 0.f, acc3 = 0.f;
    int e = beg;
    for (; e + 4 <= end; e += 4) {
        int s0 = csr_src[e], s1 = csr_src[e + 1], s2 = csr_src[e + 2], s3 = csr_src[e + 3];
        float x0 = bf2f(xb[(size_t)s0 * 64 + lane]);
        float x1 = bf2f(xb[(size_t)s1 * 64 + lane]);
        float x2 = bf2f(xb[(size_t)s2 * 64 + lane]);
        float x3 = bf2f(xb[(size_t)s3 * 64 + lane]);
        const float* a = &alpha[(size_t)e * 4];
        acc0 += a[0] * x0 + a[4] * x1 + a[8]  * x2 + a[12] * x3;
        acc1 += a[1] * x0 + a[5] * x1 + a[9]  * x2 + a[13] * x3;
        acc2 += a[2] * x0 + a[6] * x1 + a[10] * x2 + a[14] * x3;
        acc3 += a[3] * x0 + a[7] * x1 + a[11] * x2 + a[15] * x3;
    }
    for (; e < end; ++e) {
        int s = csr_src[e];
        float x = bf2f(xb[(size_t)s * 64 + lane]);
        const float* a = &alpha[(size_t)e * 4];
        acc0 += a[0] * x; acc1 += a[1] * x; acc2 += a[2] * x; acc3 += a[3] * x;
    }
    size_t o = (size_t)n * 320;
    agg[o + 0 * 64 + lane] = f2bf(acc0);
    agg[o + 1 * 64 + lane] = f2bf(acc1);
    agg[o + 2 * 64 + lane] = f2bf(acc2);
    agg[o + 3 * 64 + lane] = f2bf(acc3);
    agg[o + 256 + lane]    = xb[(size_t)n * 64 + lane];   // skip-path copy
}

// ---------------------------------------------------------------- layer-3 aggregate gather (chunked)
// Wave per node: 64 lanes x ushort4; 24 accumulators (6 heads x 4 ch); alpha via uniform loads.
__global__ __launch_bounds__(256) void gather_agg3_k(const int* __restrict__ rowptr,
                                                     const int* __restrict__ csr_src,
                                                     const unsigned short* __restrict__ hb,
                                                     const float* __restrict__ alpha,
                                                     unsigned short* __restrict__ agg,
                                                     int base) {
    int wid = threadIdx.x >> 6, lane = threadIdx.x & 63;
    int li  = blockIdx.x * 4 + wid;        // local node index within chunk
    int n   = base + li;
    int beg = rowptr[n], end = rowptr[n + 1];
    float acc[6][4];
    #pragma unroll
    for (int h = 0; h < 6; ++h)
        #pragma unroll
        for (int c = 0; c < 4; ++c) acc[h][c] = 0.f;

    int e = beg;
    for (; e + 2 <= end; e += 2) {
        int s0 = csr_src[e], s1 = csr_src[e + 1];
        const float* a0 = &alpha[(size_t)e * 6];
        const float* a1 = a0 + 6;
        ushort4 u0 = *(const ushort4*)(hb + (size_t)s0 * 256 + lane * 4);
        ushort4 u1 = *(const ushort4*)(hb + (size_t)s1 * 256 + lane * 4);
        float f0[4] = {bf2f(u0.x), bf2f(u0.y), bf2f(u0.z), bf2f(u0.w)};
        float f1[4] = {bf2f(u1.x), bf2f(u1.y), bf2f(u1.z), bf2f(u1.w)};
        #pragma unroll
        for (int h = 0; h < 6; ++h) {
            float w0 = a0[h], w1 = a1[h];
            #pragma unroll
            for (int c = 0; c < 4; ++c) acc[h][c] += w0 * f0[c] + w1 * f1[c];
        }
    }
    for (; e < end; ++e) {
        int s = csr_src[e];
        const float* a = &alpha[(size_t)e * 6];
        ushort4 u = *(const ushort4*)(hb + (size_t)s * 256 + lane * 4);
        float f[4] = {bf2f(u.x), bf2f(u.y), bf2f(u.z), bf2f(u.w)};
        #pragma unroll
        for (int h = 0; h < 6; ++h) {
            float w = a[h];
            #pragma unroll
            for (int c = 0; c < 4; ++c) acc[h][c] += w * f[c];
        }
    }
    size_t o = (size_t)li * 1792;
    #pragma unroll
    for (int h = 0; h < 6; ++h) {
        ushort4 r;
        r.x = f2bf(acc[h][0]); r.y = f2bf(acc[h][1]);
        r.z = f2bf(acc[h][2]); r.w = f2bf(acc[h][3]);
        *(ushort4*)(agg + o + h * 256 + lane * 4) = r;
    }
    *(ushort4*)(agg + o + 1536 + lane * 4) =
        *(const ushort4*)(hb + (size_t)n * 256 + lane * 4);   // skip-path copy
}

// ---------------------------------------------------------------- launch
extern "C" void kernel_launch(void* const* d_in, const int* in_sizes, int n_in,
                              void* d_out, int out_size, void* d_ws, size_t ws_size,
                              hipStream_t stream) {
    const float* x   = (const float*)d_in[0];
    const int*   ei  = (const int*)d_in[1];
    const float* W1  = (const float*)d_in[2];
    const float* a1s = (const float*)d_in[3];
    const float* a1d = (const float*)d_in[4];
    const float* b1  = (const float*)d_in[5];
    const float* Wl1 = (const float*)d_in[6];
    const float* bl1 = (const float*)d_in[7];
    const float* W2  = (const float*)d_in[8];
    const float* a2s = (const float*)d_in[9];
    const float* a2d = (const float*)d_in[10];
    const float* b2  = (const float*)d_in[11];
    const float* Wl2 = (const float*)d_in[12];
    const float* bl2 = (const float*)d_in[13];
    const float* W3  = (const float*)d_in[14];
    const float* a3s = (const float*)d_in[15];
    const float* a3d = (const float*)d_in[16];
    const float* b3  = (const float*)d_in[17];
    const float* Wl3 = (const float*)d_in[18];
    const float* bl3 = (const float*)d_in[19];

    float* out    = (float*)d_out;                 // [40000,121]
    float* hidden = out + (size_t)NN * 121;        // [40000,256]

    // workspace layout (~135 MB; agg3 aliases dead layer-1/2 buffers)
    char* ws = (char*)d_ws;
    size_t off = 0;
    auto alloc = [&](size_t bytes) { size_t o = off; off = (off + bytes + 255) & ~(size_t)255; return o; };
    int*   counts    = (int*)(ws + alloc((size_t)NN * 4));
    int*   rowptr    = (int*)(ws + alloc((size_t)(NN + 1) * 4));
    int*   blocksums = (int*)(ws + alloc(256 * 4));
    int*   csr_src   = (int*)(ws + alloc((size_t)ETOT * 4));
    float* al        = (float*)(ws + alloc((size_t)NN * 6 * 4));
    float* ar        = (float*)(ws + alloc((size_t)NN * 6 * 4));
    float* alpha     = (float*)(ws + alloc((size_t)ETOT * 6 * 4));
    unsigned short* hiddenb = (unsigned short*)(ws + alloc((size_t)NN * 256 * 2));
    unsigned short* w2c     = (unsigned short*)(ws + alloc((size_t)512 * 256 * 2));
    unsigned short* bt1     = (unsigned short*)(ws + alloc((size_t)256 * 320 * 2));
    unsigned short* bt3     = (unsigned short*)(ws + alloc((size_t)121 * 1792 * 2));
    unsigned short* vt1     = (unsigned short*)(ws + alloc((size_t)32 * 64 * 2));
    unsigned short* vt2     = (unsigned short*)(ws + alloc((size_t)32 * 256 * 2));
    unsigned short* vt3     = (unsigned short*)(ws + alloc((size_t)32 * 256 * 2));
    float* bias1s  = (float*)(ws + alloc(256 * 4));
    float* bias2s  = (float*)(ws + alloc(256 * 4));
    float* bias3s  = (float*)(ws + alloc(128 * 4));
    // UNION region: layers 1-2 use {hfeat2b[N,512], xb, h1b, agg1}; layer 3 reuses as agg3 (20000x1792)
    size_t uoff = alloc((size_t)NN * 512 * 2 + (size_t)NN * 64 * 2 +
                        (size_t)NN * 256 * 2 + (size_t)NN * 320 * 2 + 1024);
    unsigned short* hfeat2b = (unsigned short*)(ws + uoff);
    unsigned short* xb      = hfeat2b + (size_t)NN * 512;
    unsigned short* h1b     = xb + (size_t)NN * 64;
    unsigned short* agg1    = h1b + (size_t)NN * 256;
    unsigned short* agg3    = hfeat2b;   // alias: 20000*1792 = NN*896 shorts <= union size

    const int eblocks = (ETOT + 255) / 256;
    const int ablocks = NN / 4;        // 10000
    const int mg  = (NN + 127) / 128;  // 313

    // ---- prep (reads inputs only)
    xprep_k<<<(NN * 64 + 255) / 256, 256, 0, stream>>>(x, xb);
    w1prep_k<<<256, 256, 0, stream>>>(W1, Wl1, bt1);
    w2prep_k<<<512, 256, 0, stream>>>(W2, Wl2, w2c);
    w3prep_k<<<121, 256, 0, stream>>>(W3, Wl3, bt3);
    attvec2_k<<<(64 * 32 + 255) / 256, 256, 0, stream>>>(W1, a1s, a1d, vt1, 50, 64, 4, 64);
    attvec2_k<<<(256 * 32 + 255) / 256, 256, 0, stream>>>(W2, a2s, a2d, vt2, 256, 256, 4, 64);
    attvec2_k<<<(256 * 32 + 255) / 256, 256, 0, stream>>>(W3, a3s, a3d, vt3, 256, 256, 6, 121);
    biases_k<<<1, 256, 0, stream>>>(b1, bl1, b2, bl2, b3, bl3, bias1s, bias2s, bias3s);

    // ---- CSR build
    hipMemsetAsync(counts, 0, (size_t)NN * 4, stream);
    count_k<<<eblocks, 256, 0, stream>>>(ei, counts);
    scan_k<<<NBLK, 256, 0, stream>>>(counts, rowptr, blocksums, NN);
    scan_k<<<1, 256, 0, stream>>>(blocksums, blocksums, nullptr, NBLK);
    add_off_k<<<NBLK, 256, 0, stream>>>(rowptr, blocksums);
    hipMemsetAsync(counts, 0, (size_t)NN * 4, stream);  // reuse as cursor
    scatter_k<<<eblocks, 256, 0, stream>>>(ei, rowptr, counts, csr_src);

    // ---- Layer 1: aggregate-first. h1b = elu(agg1 @ bt1 + b1 + bl1)
    alar3_k<4><<<mg, 256, 0, stream>>>(xb, vt1, al, ar, NN, 64);
    attn_alpha_k<4, 4, 2><<<ablocks, 256, 0, stream>>>(rowptr, csr_src, al, ar, alpha);
    gather_agg1_k<<<ablocks, 256, 0, stream>>>(rowptr, csr_src, xb, alpha, agg1);
    gemm_bf16_k<6><<<dim3(2, mg), 256, 0, stream>>>(agg1, bt1, bias1s, nullptr, h1b, NN, 256, 320);

    // ---- Layer 2: one combined GEMM (features|skip), MFMA alar, fused gather epilogue
    gemm_bf16_k<3><<<dim3(4, mg), 256, 0, stream>>>(h1b, w2c, nullptr, nullptr, hfeat2b, NN, 512, 256);
    alar3_k<4><<<mg, 256, 0, stream>>>(h1b, vt2, al, ar, NN, 256);
    attn_alpha_k<4, 4, 2><<<ablocks, 256, 0, stream>>>(rowptr, csr_src, al, ar, alpha);
    gather_concat2_k<<<ablocks, 256, 0, stream>>>(rowptr, csr_src, hfeat2b, alpha, bias2s, hidden, hiddenb);

    // ---- Layer 3: aggregate-first, 2 chunks of 20000 (agg3 aliases dead buffers)
    alar3_k<6><<<mg, 256, 0, stream>>>(hiddenb, vt3, al, ar, NN, 256);
    attn_alpha_k<6, 8, 3><<<ablocks, 256, 0, stream>>>(rowptr, csr_src, al, ar, alpha);
    for (int c = 0; c < 2; ++c) {
        int base = c * 20000;
        gather_agg3_k<<<5000, 256, 0, stream>>>(rowptr, csr_src, hiddenb, alpha, agg3, base);
        gemm_skinny_k<<<625, 256, 0, stream>>>(agg3, bt3, bias3s,
                                               out + (size_t)base * 121, 20000, 121, 1792);
    }
}